// Round 2
// baseline (221.900 us; speedup 1.0000x reference)
//
#include <hip/hip_runtime.h>
#include <math.h>

#define N_PROT 50000
#define N_SUB  2000
#define D_PROT 256
#define D_SUB  256
#define D_PROJ 128
#define KW     16
#define N_INT  64
#define NWIN   (N_PROT - KW + 1)

// output layout (floats)
#define OUT_SUB (N_PROT * D_PROT)                 // 12,800,000
#define OUT_IDX (OUT_SUB + N_SUB * D_SUB)         // 13,312,000

// ws layout (float/uint indices into ws)
#define WS_PACK  0                                // [0..1] packed argmax u64
#define WS_REACT 2                                // [2..129] reaction
#define WS_CNT2  130                              // patch-election counter (uint)
#define WS_CCNT  132                              // [132..180] per-chunk counters (49 uint)
#define WS_MASK  184                              // [184..246] int_index row bitmap (63 uint)
#define WS_U1    248                              // u1 = Wp @ w1 (256), 16B aligned
#define WS_U2    504                              // u2 = Wp @ ones (256)
#define WS_G     760                              // g[N_PROT]
#define WS_P     (WS_G + N_PROT)                  // P[N_PROT]

#define PB   1563                                 // 1563*32 = 50016 >= 50000 rows
#define SB   64                                   // sub-copy blocks
#define NBLK (1 + SB + PB)                        // reaction + sub + stream = 1628
#define NWCH 49                                   // window chunks of 1024
// chunk c needs g/P rows [1024c, min(1024c+1038, N_PROT-1)] -> row-blocks
// [32c, 32c+32] = 33 producers, except last chunk: rows up to 49999 -> 27.
#define EXPC(c) ((c) == NWCH - 1 ? 27 : 33)

typedef float v4f __attribute__((ext_vector_type(4)));

union SMem {
  struct { int sidx[N_INT]; float ssum[D_SUB]; } react;
  struct { float sg[1024 + KW]; float sp[1024 + KW]; unsigned long long wred[4]; } win;
  struct {
    float aprot[KW][D_PROT];                      // 16 KB
    float attn[KW];
    float v[D_PROT];
    float part[2][D_PROJ];
    float ts[D_PROJ];
    float pdelta[D_PROT];
    float sdelta[D_SUB];
    int   sidx[N_INT];
  } patch;                                        // ~21 KB
};

// =================== K0: flags + mask + u1/u2 (1 block) ======================
__global__ __launch_bounds__(256) void k_init(
    const float* __restrict__ Wp, const float* __restrict__ wa,
    const int* __restrict__ int_index, float* __restrict__ ws) {
  const int tid = threadIdx.x;
  __shared__ unsigned smask[63];
  __shared__ float swa[D_PROJ];
  if (tid < 63) smask[tid] = 0u;
  if (tid < D_PROJ) swa[tid] = wa[tid];
  __syncthreads();
  if (tid < N_INT) {
    const int ii = int_index[tid];
    atomicOr(&smask[ii >> 5], 1u << (ii & 31));
  }
  __syncthreads();
  if (tid < 63) ((unsigned*)ws)[WS_MASK + tid] = smask[tid];
  if (tid == 0) {
    *((unsigned long long*)ws) = 0ull;            // WS_PACK
    ((unsigned*)ws)[WS_CNT2] = 0u;
  }
  if (tid < NWCH) ((unsigned*)ws)[WS_CCNT + tid] = 0u;
  // u1[k] = sum_j Wp[k][j]*wa[j];  u2[k] = sum_j Wp[k][j]   (k = tid)
  float s1 = 0.f, s2 = 0.f;
  const v4f* wrow = (const v4f*)&Wp[tid * D_PROJ];
  #pragma unroll 8
  for (int j4 = 0; j4 < D_PROJ / 4; ++j4) {
    v4f w = wrow[j4];
    v4f a = *(const v4f*)&swa[j4 * 4];
    s1 = fmaf(w.x, a.x, fmaf(w.y, a.y, fmaf(w.z, a.z, fmaf(w.w, a.w, s1))));
    s2 += w.x + w.y + w.z + w.w;
  }
  ws[WS_U1 + tid] = s1;
  ws[WS_U2 + tid] = s2;
}

// ---------------- window-chunk argmax (1024 windows) ----------------
__device__ void do_chunk(SMem& sm, const int tid, const int lane,
                         const int wave, const int chunk,
                         float* __restrict__ ws) {
  const int w0 = chunk * 1024;
  for (int i = tid; i < 1024 + KW - 1; i += 256) {
    const int idx = w0 + i;
    const bool ok = idx < N_PROT;
    sm.win.sg[i] = ok ? ws[WS_G + idx] : -1e30f;
    sm.win.sp[i] = ok ? ws[WS_P + idx] : 0.f;
  }
  __syncthreads();
  unsigned long long best = 0ull;
  #pragma unroll
  for (int it = 0; it < 4; ++it) {
    const int i = tid + it * 256;
    const int w = w0 + i;
    if (w < NWIN) {
      float m = sm.win.sg[i];
      #pragma unroll
      for (int k = 1; k < KW; ++k) m = fmaxf(m, sm.win.sg[i + k]);
      float s = 0.f, t = 0.f;
      #pragma unroll
      for (int k = 0; k < KW; ++k) {
        float e = expf(sm.win.sg[i + k] - m);
        s += e;
        t = fmaf(e, sm.win.sp[i + k], t);
      }
      t /= s;   // + const dropped: argmax-invariant
      unsigned int bb = __float_as_uint(t);
      unsigned int u = bb ^ ((bb & 0x80000000u) ? 0xFFFFFFFFu : 0x80000000u);
      unsigned long long cand = ((unsigned long long)u << 32) |
                                (unsigned long long)(0xFFFFFFFFu - (unsigned)w);
      if (cand > best) best = cand;
    }
  }
  #pragma unroll
  for (int off = 32; off > 0; off >>= 1) {
    unsigned long long o = __shfl_xor(best, off, 64);
    if (o > best) best = o;
  }
  if (lane == 0) sm.win.wred[wave] = best;
  __syncthreads();
  if (tid == 0) {
    unsigned long long b2 = sm.win.wred[0];
    for (int i = 1; i < 4; ++i) if (sm.win.wred[i] > b2) b2 = sm.win.wred[i];
    atomicMax((unsigned long long*)ws, b2);       // device-scope
  }
  __syncthreads();
}

// ---------------- final patch (256 thr) ----------------
__device__ void do_patch(
    SMem& sm, const int tid,
    const float* __restrict__ prot, const float* __restrict__ sub_node,
    const int* __restrict__ int_index, const float* __restrict__ Wp,
    const float* __restrict__ bp, const float* __restrict__ sub_out,
    const float* __restrict__ prot_out, float* __restrict__ ws,
    float* __restrict__ out) {
  __shared__ int s_wtop;
  if (tid == 0) {
    unsigned long long pk = atomicMax((unsigned long long*)ws, 0ull);
    s_wtop = (int)(0xFFFFFFFFu - (unsigned)(pk & 0xFFFFFFFFull));
  }
  __syncthreads();
  const int wtop = s_wtop;
  #pragma unroll
  for (int it = 0; it < 4; ++it) {                // load 16 window rows
    const int f = tid + it * 256;
    const int row = f >> 6, c4 = (f & 63) * 4;
    *(v4f*)&sm.patch.aprot[row][c4] =
        *(const v4f*)&prot[(wtop + row) * D_PROT + c4];
  }
  if (tid < N_INT) sm.patch.sidx[tid] = int_index[tid];
  if (tid == 0) {   // softmax over g window (shift-invariant vs ref)
    float m = ws[WS_G + wtop];
    for (int k = 1; k < KW; ++k) m = fmaxf(m, ws[WS_G + wtop + k]);
    float e[KW], s = 0.f;
    for (int k = 0; k < KW; ++k) { e[k] = expf(ws[WS_G + wtop + k] - m); s += e[k]; }
    for (int k = 0; k < KW; ++k) sm.patch.attn[k] = e[k] / s;
  }
  __syncthreads();
  {  // v = attn @ A_window (sum(attn)=1 absorbs bp)
    float a = 0.f;
    #pragma unroll
    for (int k = 0; k < KW; ++k) a = fmaf(sm.patch.attn[k], sm.patch.aprot[k][tid], a);
    sm.patch.v[tid] = a;
  }
  __syncthreads();
  {  // ts partials: 2 slices x 128 d each
    const int j = tid & 127, sl = tid >> 7;
    float p = 0.f;
    const float* wp = Wp + (sl * 128) * D_PROJ + j;
    #pragma unroll 8
    for (int d = 0; d < 128; ++d) p = fmaf(sm.patch.v[sl * 128 + d], wp[d * D_PROJ], p);
    sm.patch.part[sl][j] = p;
  }
  __syncthreads();
  if (tid < D_PROJ)
    sm.patch.ts[tid] = ws[WS_REACT + tid] + bp[tid] +
                       sm.patch.part[0][tid] + sm.patch.part[1][tid];
  __syncthreads();
  {  // pdelta/sdelta: one d per thread, coalesced over j rows
    float pp = 0.f, ss = 0.f;
    #pragma unroll 8
    for (int j = 0; j < D_PROJ; ++j) {
      const float t = sm.patch.ts[j];
      pp = fmaf(t, prot_out[j * D_PROT + tid], pp);
      ss = fmaf(t, sub_out[j * D_SUB + tid], ss);
    }
    sm.patch.pdelta[tid] = pp; sm.patch.sdelta[tid] = ss;
  }
  __syncthreads();
  #pragma unroll
  for (int it = 0; it < 4; ++it) {                // write 16 prot rows
    const int f = tid + it * 256;
    const int row = f >> 6, c4 = (f & 63) * 4;
    v4f a = *(v4f*)&sm.patch.aprot[row][c4];
    v4f d = *(v4f*)&sm.patch.pdelta[c4];
    a.x += d.x; a.y += d.y; a.z += d.z; a.w += d.w;
    *(v4f*)&out[(wtop + row) * D_PROT + c4] = a;
  }
  #pragma unroll
  for (int it = 0; it < 16; ++it) {               // write 64 sub rows (dups: same value)
    const int f = tid + it * 256;                 // 4096 float4 over 64 rows
    const int row = f >> 6, c4 = (f & 63) * 4;
    const int rr = sm.patch.sidx[row];
    v4f sv = *(const v4f*)&sub_node[rr * D_SUB + c4];
    v4f d = *(v4f*)&sm.patch.sdelta[c4];
    sv.x += d.x; sv.y += d.y; sv.z += d.z; sv.w += d.w;
    *(v4f*)&out[OUT_SUB + rr * D_SUB + c4] = sv;
  }
}

// =================== K1: fused stream + reaction + windows + patch ===========
__global__ __launch_bounds__(256) void k_fused(
    const float* __restrict__ prot, const float* __restrict__ sub_node,
    const int* __restrict__ int_index, const float* __restrict__ Wp,
    const float* __restrict__ bp, const float* __restrict__ Ws,
    const float* __restrict__ bs, const float* __restrict__ sub_out,
    const float* __restrict__ prot_out, float* __restrict__ out,
    float* __restrict__ ws) {
  __shared__ SMem sm;
  __shared__ int s_t2, s_nown, s_own[2];
  const int tid = threadIdx.x, lane = tid & 63, wave = tid >> 6;
  const int b = blockIdx.x;

  if (b >= 1 && b <= SB) {
    // sub-node copy, skipping int_index rows (patch is their sole writer)
    const int sb = b - 1;
    const unsigned* mask = (const unsigned*)ws + WS_MASK;
    #pragma unroll
    for (int i = 0; i < 8; ++i) {
      const int gi = sb * 2048 + i * 256 + tid;
      if (gi < (N_SUB * D_SUB) / 4) {
        const int row = gi >> 6;
        if (!((mask[row >> 5] >> (row & 31)) & 1u))
          __builtin_nontemporal_store(*(const v4f*)&sub_node[gi * 4],
                                      (v4f*)&out[OUT_SUB + gi * 4]);
      }
    }
    return;
  }

  if (b == 0) {
    // reaction GEMV + idx passthrough + L3 warm of prot_out/sub_out
    if (tid < N_INT) {
      const int ii = int_index[tid];
      sm.react.sidx[tid] = ii;
      out[OUT_IDX + tid] = (float)ii;
    }
    __syncthreads();
    float acc = 0.f;
    #pragma unroll 8
    for (int i = 0; i < N_INT; ++i) acc += sub_node[sm.react.sidx[i] * D_SUB + tid];
    sm.react.ssum[tid] = acc;
    __syncthreads();
    if (tid < D_PROJ) {
      float r = 64.0f * bs[tid];
      #pragma unroll 8
      for (int d = 0; d < D_SUB; ++d) r = fmaf(sm.react.ssum[d], Ws[d * D_PROJ + tid], r);
      ws[WS_REACT + tid] = r;
    }
    float wsum = 0.f;
    for (int i = tid; i < (D_PROJ * D_PROT) / 4; i += 256) {
      v4f a = ((const v4f*)prot_out)[i];
      v4f c = ((const v4f*)sub_out)[i];
      wsum += a.x + c.x;
    }
    asm volatile("" :: "v"(wsum));
    __syncthreads();                              // all stores drained per-wave
    if (tid == 0) {
      unsigned old = __hip_atomic_fetch_add(&((unsigned*)ws)[WS_CNT2], 1u,
                                            __ATOMIC_RELEASE,
                                            __HIP_MEMORY_SCOPE_AGENT);
      s_t2 = (int)old + 1;
    }
    __syncthreads();
    if (s_t2 != NWCH + 1) return;                 // (block 0 last: do the patch)
    __builtin_amdgcn_fence(__ATOMIC_ACQUIRE, "agent");
    do_patch(sm, tid, prot, sub_node, int_index, Wp, bp, sub_out, prot_out,
             ws, out);
    return;
  }

  // ---------------- prot stream: copy + g/P ----------------
  const int sbid = b - 1 - SB;
  {
    const v4f c1 = *(const v4f*)&ws[WS_U1 + lane * 4];
    const v4f c2 = *(const v4f*)&ws[WS_U2 + lane * 4];
    const int rbase = sbid * 32 + wave * 8;
    if (rbase + 8 <= N_PROT) {
      v4f av[8];
      #pragma unroll
      for (int i = 0; i < 8; ++i)
        av[i] = *(const v4f*)&prot[(rbase + i) * D_PROT + lane * 4];
      #pragma unroll
      for (int i = 0; i < 8; ++i)
        *(v4f*)&out[(rbase + i) * D_PROT + lane * 4] = av[i];
      #pragma unroll
      for (int i = 0; i < 8; ++i) {
        float g = av[i].x * c1.x + av[i].y * c1.y + av[i].z * c1.z + av[i].w * c1.w;
        float p = av[i].x * c2.x + av[i].y * c2.y + av[i].z * c2.z + av[i].w * c2.w;
        #pragma unroll
        for (int off = 32; off > 0; off >>= 1) {
          g += __shfl_xor(g, off, 64);
          p += __shfl_xor(p, off, 64);
        }
        if (lane == 0) {
          const int r = rbase + i;
          ws[WS_G + r] = g; ws[WS_P + r] = p;
        }
      }
    } else {
      for (int i = 0; i < 8; ++i) {
        const int r = rbase + i;
        if (r >= N_PROT) break;
        const v4f av = *(const v4f*)&prot[r * D_PROT + lane * 4];
        *(v4f*)&out[r * D_PROT + lane * 4] = av;
        float g = av.x * c1.x + av.y * c1.y + av.z * c1.z + av.w * c1.w;
        float p = av.x * c2.x + av.y * c2.y + av.z * c2.z + av.w * c2.w;
        for (int off = 32; off > 0; off >>= 1) {
          g += __shfl_xor(g, off, 64);
          p += __shfl_xor(p, off, 64);
        }
        if (lane == 0) { ws[WS_G + r] = g; ws[WS_P + r] = p; }
      }
    }
  }

  // ---------------- producer-counted chunk handoff (no waiting) ----------------
  __syncthreads();                                // all waves' g/P + copies drained
  if (tid == 0) {
    unsigned* ccnt = (unsigned*)ws + WS_CCNT;
    const int c1 = sbid >> 5;
    int n = 0, o0 = -1, o1 = -1;
    unsigned o = __hip_atomic_fetch_add(&ccnt[c1], 1u, __ATOMIC_RELEASE,
                                        __HIP_MEMORY_SCOPE_AGENT);
    if ((int)o == EXPC(c1) - 1) { o0 = c1; n = 1; }
    if ((sbid & 31) == 0 && c1 > 0) {
      o = __hip_atomic_fetch_add(&ccnt[c1 - 1], 1u, __ATOMIC_RELEASE,
                                 __HIP_MEMORY_SCOPE_AGENT);
      if ((int)o == EXPC(c1 - 1) - 1) { if (n) o1 = c1 - 1; else o0 = c1 - 1; ++n; }
    }
    s_nown = n; s_own[0] = o0; s_own[1] = o1;
  }
  __syncthreads();
  const int nown = s_nown;
  if (nown == 0) return;
  __builtin_amdgcn_fence(__ATOMIC_ACQUIRE, "agent");  // g/P of all producers visible
  for (int i = 0; i < nown; ++i)
    do_chunk(sm, tid, lane, wave, s_own[i], ws);

  if (tid == 0) {
    unsigned old = __hip_atomic_fetch_add(&((unsigned*)ws)[WS_CNT2], (unsigned)nown,
                                          __ATOMIC_RELEASE,
                                          __HIP_MEMORY_SCOPE_AGENT);
    s_t2 = (int)old + nown;
  }
  __syncthreads();
  if (s_t2 != NWCH + 1) return;                   // target: 49 chunks + react block
  __builtin_amdgcn_fence(__ATOMIC_ACQUIRE, "agent");
  do_patch(sm, tid, prot, sub_node, int_index, Wp, bp, sub_out, prot_out,
           ws, out);
}

extern "C" void kernel_launch(void* const* d_in, const int* in_sizes, int n_in,
                              void* d_out, int out_size, void* d_ws, size_t ws_size,
                              hipStream_t stream) {
  const float* prot     = (const float*)d_in[0];
  const float* sub      = (const float*)d_in[1];
  const int*   idx      = (const int*)d_in[2];
  const float* Wp       = (const float*)d_in[3];
  const float* bp       = (const float*)d_in[4];
  const float* Ws       = (const float*)d_in[5];
  const float* bs       = (const float*)d_in[6];
  const float* wa       = (const float*)d_in[7];
  // d_in[8] = ba unused (cancels in softmax); wa[128:] unused (constant in g)
  const float* sub_out  = (const float*)d_in[9];
  const float* prot_out = (const float*)d_in[10];
  float* out = (float*)d_out;
  float* ws  = (float*)d_ws;

  k_init<<<1, 256, 0, stream>>>(Wp, wa, idx, ws);
  k_fused<<<NBLK, 256, 0, stream>>>(prot, sub, idx, Wp, bp, Ws, bs,
                                    sub_out, prot_out, out, ws);
}

// Round 3
// 168.811 us; speedup vs baseline: 1.3145x; 1.3145x over previous
//
#include <hip/hip_runtime.h>
#include <math.h>

#define N_PROT 50000
#define N_SUB  2000
#define D_PROT 256
#define D_SUB  256
#define D_PROJ 128
#define KW     16
#define N_INT  64
#define NWIN   (N_PROT - KW + 1)

// output layout (floats)
#define OUT_SUB (N_PROT * D_PROT)                 // 12,800,000
#define OUT_IDX (OUT_SUB + N_SUB * D_SUB)         // 13,312,000

// ws layout (float/uint indices into ws)
#define WS_PACK  0                                // [0..1] packed argmax u64
#define WS_REACT 2                                // [2..129] reaction
#define WS_CCNT  132                              // [132..180] per-chunk counters (49 uint)
#define WS_U1    248                              // u1 = Wp @ w1 (256), 16B aligned
#define WS_U2    504                              // u2 = Wp @ ones (256)
#define WS_G     760                              // g[N_PROT]
#define WS_P     (WS_G + N_PROT)                  // P[N_PROT]

#define PB   1563                                 // 1563*32 = 50016 >= 50000 rows
#define SB   64                                   // sub-copy blocks
#define NBLK (1 + SB + PB)                        // reaction + sub + stream = 1628
#define NWCH 49                                   // window chunks of 1024
// chunk c consumes g/P row-blocks [32c, 32c+32] -> 33 producers (last: 27)
#define EXPC(c) ((c) == NWCH - 1 ? 27 : 33)

typedef float v4f __attribute__((ext_vector_type(4)));

union SMem {
  struct { int sidx[N_INT]; float ssum[D_SUB]; } react;
  struct { float sg[1024 + KW]; float sp[1024 + KW]; unsigned long long wred[4]; } win;
};                                                // ~8.4 KB

// =================== K0: flags + u1/u2 (1 block) =============================
__global__ __launch_bounds__(256) void k_init(
    const float* __restrict__ Wp, const float* __restrict__ wa,
    float* __restrict__ ws) {
  const int tid = threadIdx.x;
  __shared__ float swa[D_PROJ];
  if (tid < D_PROJ) swa[tid] = wa[tid];
  if (tid == 0) *((unsigned long long*)ws) = 0ull;    // WS_PACK
  if (tid < NWCH) ((unsigned*)ws)[WS_CCNT + tid] = 0u;
  __syncthreads();
  // u1[k] = sum_j Wp[k][j]*wa[j];  u2[k] = sum_j Wp[k][j]   (k = tid)
  float s1 = 0.f, s2 = 0.f;
  const v4f* wrow = (const v4f*)&Wp[tid * D_PROJ];
  #pragma unroll 8
  for (int j4 = 0; j4 < D_PROJ / 4; ++j4) {
    v4f w = wrow[j4];
    v4f a = *(const v4f*)&swa[j4 * 4];
    s1 = fmaf(w.x, a.x, fmaf(w.y, a.y, fmaf(w.z, a.z, fmaf(w.w, a.w, s1))));
    s2 += w.x + w.y + w.z + w.w;
  }
  ws[WS_U1 + tid] = s1;
  ws[WS_U2 + tid] = s2;
}

// ---------------- window-chunk argmax (1024 windows) ----------------
// g/P read with relaxed agent-scope loads (sc-bit, L2-bypass: coherent
// per-line, no cache-maintenance). Producers drained vmcnt before ticket.
__device__ void do_chunk(SMem& sm, const int tid, const int lane,
                         const int wave, const int chunk,
                         float* __restrict__ ws) {
  const int w0 = chunk * 1024;
  for (int i = tid; i < 1024 + KW - 1; i += 256) {
    const int idx = w0 + i;
    const bool ok = idx < N_PROT;
    sm.win.sg[i] = ok ? __hip_atomic_load(&ws[WS_G + idx], __ATOMIC_RELAXED,
                                          __HIP_MEMORY_SCOPE_AGENT) : -1e30f;
    sm.win.sp[i] = ok ? __hip_atomic_load(&ws[WS_P + idx], __ATOMIC_RELAXED,
                                          __HIP_MEMORY_SCOPE_AGENT) : 0.f;
  }
  __syncthreads();
  unsigned long long best = 0ull;
  #pragma unroll
  for (int it = 0; it < 4; ++it) {
    const int i = tid + it * 256;
    const int w = w0 + i;
    if (w < NWIN) {
      float m = sm.win.sg[i];
      #pragma unroll
      for (int k = 1; k < KW; ++k) m = fmaxf(m, sm.win.sg[i + k]);
      float s = 0.f, t = 0.f;
      #pragma unroll
      for (int k = 0; k < KW; ++k) {
        float e = expf(sm.win.sg[i + k] - m);
        s += e;
        t = fmaf(e, sm.win.sp[i + k], t);
      }
      t /= s;   // + const dropped: argmax-invariant
      unsigned int bb = __float_as_uint(t);
      unsigned int u = bb ^ ((bb & 0x80000000u) ? 0xFFFFFFFFu : 0x80000000u);
      unsigned long long cand = ((unsigned long long)u << 32) |
                                (unsigned long long)(0xFFFFFFFFu - (unsigned)w);
      if (cand > best) best = cand;
    }
  }
  #pragma unroll
  for (int off = 32; off > 0; off >>= 1) {
    unsigned long long o = __shfl_xor(best, off, 64);
    if (o > best) best = o;
  }
  if (lane == 0) sm.win.wred[wave] = best;
  __syncthreads();
  if (tid == 0) {
    unsigned long long b2 = sm.win.wred[0];
    for (int i = 1; i < 4; ++i) if (sm.win.wred[i] > b2) b2 = sm.win.wred[i];
    atomicMax((unsigned long long*)ws, b2);       // device-scope RMW
  }
  __syncthreads();
}

// =================== K1: fused stream + reaction + window argmax =============
__global__ __launch_bounds__(256) void k_fused(
    const float* __restrict__ prot, const float* __restrict__ sub_node,
    const int* __restrict__ int_index, const float* __restrict__ Ws,
    const float* __restrict__ bs, const float* __restrict__ sub_out,
    const float* __restrict__ prot_out, float* __restrict__ out,
    float* __restrict__ ws) {
  __shared__ SMem sm;
  __shared__ int s_nown, s_own[2];
  const int tid = threadIdx.x, lane = tid & 63, wave = tid >> 6;
  const int b = blockIdx.x;

  if (b >= 1 && b <= SB) {
    // sub-node copy (int_index rows overwritten later by k_patch)
    const int sb = b - 1;
    #pragma unroll
    for (int i = 0; i < 8; ++i) {
      const int gi = sb * 2048 + i * 256 + tid;
      if (gi < (N_SUB * D_SUB) / 4)
        __builtin_nontemporal_store(*(const v4f*)&sub_node[gi * 4],
                                    (v4f*)&out[OUT_SUB + gi * 4]);
    }
    return;
  }

  if (b == 0) {
    // reaction GEMV + idx passthrough + L3 warm of prot_out/sub_out
    if (tid < N_INT) {
      const int ii = int_index[tid];
      sm.react.sidx[tid] = ii;
      out[OUT_IDX + tid] = (float)ii;
    }
    __syncthreads();
    float acc = 0.f;
    #pragma unroll 8
    for (int i = 0; i < N_INT; ++i) acc += sub_node[sm.react.sidx[i] * D_SUB + tid];
    sm.react.ssum[tid] = acc;
    __syncthreads();
    if (tid < D_PROJ) {
      float r = 64.0f * bs[tid];
      #pragma unroll 8
      for (int d = 0; d < D_SUB; ++d) r = fmaf(sm.react.ssum[d], Ws[d * D_PROJ + tid], r);
      ws[WS_REACT + tid] = r;                     // plain: k_patch reads across boundary
    }
    float wsum = 0.f;
    for (int i = tid; i < (D_PROJ * D_PROT) / 4; i += 256) {
      v4f a = ((const v4f*)prot_out)[i];
      v4f c = ((const v4f*)sub_out)[i];
      wsum += a.x + c.x;
    }
    asm volatile("" :: "v"(wsum));
    return;
  }

  // ---------------- prot stream: copy + g/P ----------------
  const int sbid = b - 1 - SB;
  {
    const v4f c1 = *(const v4f*)&ws[WS_U1 + lane * 4];
    const v4f c2 = *(const v4f*)&ws[WS_U2 + lane * 4];
    const int rbase = sbid * 32 + wave * 8;
    if (rbase + 8 <= N_PROT) {
      v4f av[8];
      #pragma unroll
      for (int i = 0; i < 8; ++i)
        av[i] = *(const v4f*)&prot[(rbase + i) * D_PROT + lane * 4];
      #pragma unroll
      for (int i = 0; i < 8; ++i)
        *(v4f*)&out[(rbase + i) * D_PROT + lane * 4] = av[i];
      #pragma unroll
      for (int i = 0; i < 8; ++i) {
        float g = av[i].x * c1.x + av[i].y * c1.y + av[i].z * c1.z + av[i].w * c1.w;
        float p = av[i].x * c2.x + av[i].y * c2.y + av[i].z * c2.z + av[i].w * c2.w;
        #pragma unroll
        for (int off = 32; off > 0; off >>= 1) {
          g += __shfl_xor(g, off, 64);
          p += __shfl_xor(p, off, 64);
        }
        if (lane == 0) {
          const int r = rbase + i;
          __hip_atomic_store(&ws[WS_G + r], g, __ATOMIC_RELAXED,
                             __HIP_MEMORY_SCOPE_AGENT);
          __hip_atomic_store(&ws[WS_P + r], p, __ATOMIC_RELAXED,
                             __HIP_MEMORY_SCOPE_AGENT);
        }
      }
    } else {
      for (int i = 0; i < 8; ++i) {
        const int r = rbase + i;
        if (r >= N_PROT) break;
        const v4f av = *(const v4f*)&prot[r * D_PROT + lane * 4];
        *(v4f*)&out[r * D_PROT + lane * 4] = av;
        float g = av.x * c1.x + av.y * c1.y + av.z * c1.z + av.w * c1.w;
        float p = av.x * c2.x + av.y * c2.y + av.z * c2.z + av.w * c2.w;
        for (int off = 32; off > 0; off >>= 1) {
          g += __shfl_xor(g, off, 64);
          p += __shfl_xor(p, off, 64);
        }
        if (lane == 0) {
          __hip_atomic_store(&ws[WS_G + r], g, __ATOMIC_RELAXED,
                             __HIP_MEMORY_SCOPE_AGENT);
          __hip_atomic_store(&ws[WS_P + r], p, __ATOMIC_RELAXED,
                             __HIP_MEMORY_SCOPE_AGENT);
        }
      }
    }
  }

  // ---------- producer-counted chunk handoff (relaxed: no cache maint.) ------
  // __syncthreads drains each wave's vmcnt -> our sc1 g/P stores are at the
  // coherence point before the ticket increment below.
  __syncthreads();
  if (tid == 0) {
    unsigned* ccnt = (unsigned*)ws + WS_CCNT;
    const int c1 = sbid >> 5;
    int n = 0, o0 = -1, o1 = -1;
    unsigned o = __hip_atomic_fetch_add(&ccnt[c1], 1u, __ATOMIC_RELAXED,
                                        __HIP_MEMORY_SCOPE_AGENT);
    if ((int)o == EXPC(c1) - 1) { o0 = c1; n = 1; }
    if ((sbid & 31) == 0 && c1 > 0) {
      o = __hip_atomic_fetch_add(&ccnt[c1 - 1], 1u, __ATOMIC_RELAXED,
                                 __HIP_MEMORY_SCOPE_AGENT);
      if ((int)o == EXPC(c1 - 1) - 1) { if (n) o1 = c1 - 1; else o0 = c1 - 1; ++n; }
    }
    s_nown = n; s_own[0] = o0; s_own[1] = o1;
  }
  __syncthreads();
  const int nown = s_nown;
  if (nown == 0) return;
  for (int i = 0; i < nown; ++i)
    do_chunk(sm, tid, lane, wave, s_own[i], ws);
}

// =================== K2: final patch (1 block, after boundary) ===============
__global__ __launch_bounds__(256) void k_patch(
    const float* __restrict__ prot, const float* __restrict__ sub_node,
    const int* __restrict__ int_index, const float* __restrict__ Wp,
    const float* __restrict__ bp, const float* __restrict__ sub_out,
    const float* __restrict__ prot_out, float* __restrict__ ws,
    float* __restrict__ out) {
  __shared__ float aprot[KW][D_PROT];             // 16 KB
  __shared__ float attn[KW];
  __shared__ float v[D_PROT];
  __shared__ float part[2][D_PROJ];
  __shared__ float ts[D_PROJ];
  __shared__ float pdelta[D_PROT], sdelta[D_SUB];
  __shared__ int   sidx[N_INT];
  __shared__ int   s_wtop;
  const int tid = threadIdx.x;
  if (tid == 0) {
    unsigned long long pk = *(const unsigned long long*)ws;
    s_wtop = (int)(0xFFFFFFFFu - (unsigned)(pk & 0xFFFFFFFFull));
  }
  if (tid < N_INT) sidx[tid] = int_index[tid];
  __syncthreads();
  const int wtop = s_wtop;
  #pragma unroll
  for (int it = 0; it < 4; ++it) {                // load 16 window rows
    const int f = tid + it * 256;
    const int row = f >> 6, c4 = (f & 63) * 4;
    *(v4f*)&aprot[row][c4] = *(const v4f*)&prot[(wtop + row) * D_PROT + c4];
  }
  if (tid == 0) {   // softmax over g window (shift-invariant vs ref)
    float m = ws[WS_G + wtop];
    for (int k = 1; k < KW; ++k) m = fmaxf(m, ws[WS_G + wtop + k]);
    float e[KW], s = 0.f;
    for (int k = 0; k < KW; ++k) { e[k] = expf(ws[WS_G + wtop + k] - m); s += e[k]; }
    for (int k = 0; k < KW; ++k) attn[k] = e[k] / s;
  }
  __syncthreads();
  {  // v = attn @ A_window (sum(attn)=1 absorbs bp)
    float a = 0.f;
    #pragma unroll
    for (int k = 0; k < KW; ++k) a = fmaf(attn[k], aprot[k][tid], a);
    v[tid] = a;
  }
  __syncthreads();
  {  // ts partials: 2 slices x 128 d each
    const int j = tid & 127, sl = tid >> 7;
    float p = 0.f;
    const float* wp = Wp + (sl * 128) * D_PROJ + j;
    #pragma unroll 8
    for (int d = 0; d < 128; ++d) p = fmaf(v[sl * 128 + d], wp[d * D_PROJ], p);
    part[sl][j] = p;
  }
  __syncthreads();
  if (tid < D_PROJ)
    ts[tid] = ws[WS_REACT + tid] + bp[tid] + part[0][tid] + part[1][tid];
  __syncthreads();
  {  // pdelta/sdelta: one d per thread, coalesced over j rows
    float pp = 0.f, ss = 0.f;
    #pragma unroll 8
    for (int j = 0; j < D_PROJ; ++j) {
      const float t = ts[j];
      pp = fmaf(t, prot_out[j * D_PROT + tid], pp);
      ss = fmaf(t, sub_out[j * D_SUB + tid], ss);
    }
    pdelta[tid] = pp; sdelta[tid] = ss;
  }
  __syncthreads();
  #pragma unroll
  for (int it = 0; it < 4; ++it) {                // write 16 prot rows
    const int f = tid + it * 256;
    const int row = f >> 6, c4 = (f & 63) * 4;
    v4f a = *(v4f*)&aprot[row][c4];
    v4f d = *(v4f*)&pdelta[c4];
    a.x += d.x; a.y += d.y; a.z += d.z; a.w += d.w;
    *(v4f*)&out[(wtop + row) * D_PROT + c4] = a;
  }
  #pragma unroll
  for (int it = 0; it < 16; ++it) {               // write 64 sub rows (dups: same value)
    const int f = tid + it * 256;                 // 4096 float4 over 64 rows
    const int row = f >> 6, c4 = (f & 63) * 4;
    const int rr = sidx[row];
    v4f sv = *(const v4f*)&sub_node[rr * D_SUB + c4];
    v4f d = *(v4f*)&sdelta[c4];
    sv.x += d.x; sv.y += d.y; sv.z += d.z; sv.w += d.w;
    *(v4f*)&out[OUT_SUB + rr * D_SUB + c4] = sv;
  }
}

extern "C" void kernel_launch(void* const* d_in, const int* in_sizes, int n_in,
                              void* d_out, int out_size, void* d_ws, size_t ws_size,
                              hipStream_t stream) {
  const float* prot     = (const float*)d_in[0];
  const float* sub      = (const float*)d_in[1];
  const int*   idx      = (const int*)d_in[2];
  const float* Wp       = (const float*)d_in[3];
  const float* bp       = (const float*)d_in[4];
  const float* Ws       = (const float*)d_in[5];
  const float* bs       = (const float*)d_in[6];
  const float* wa       = (const float*)d_in[7];
  // d_in[8] = ba unused (cancels in softmax); wa[128:] unused (constant in g)
  const float* sub_out  = (const float*)d_in[9];
  const float* prot_out = (const float*)d_in[10];
  float* out = (float*)d_out;
  float* ws  = (float*)d_ws;

  k_init<<<1, 256, 0, stream>>>(Wp, wa, ws);
  k_fused<<<NBLK, 256, 0, stream>>>(prot, sub, idx, Ws, bs,
                                    sub_out, prot_out, out, ws);
  k_patch<<<1, 256, 0, stream>>>(prot, sub, idx, Wp, bp, sub_out, prot_out,
                                 ws, out);
}

// Round 4
// 160.773 us; speedup vs baseline: 1.3802x; 1.0500x over previous
//
#include <hip/hip_runtime.h>
#include <math.h>

#define N_PROT 50000
#define N_SUB  2000
#define D_PROT 256
#define D_SUB  256
#define D_PROJ 128
#define KW     16
#define N_INT  64
#define NWIN   (N_PROT - KW + 1)

// output layout (floats)
#define OUT_SUB (N_PROT * D_PROT)                 // 12,800,000
#define OUT_IDX (OUT_SUB + N_SUB * D_SUB)         // 13,312,000

// ws layout (floats)
#define WS_PACK  0                                // [0..1] packed argmax u64
#define WS_CNT   130                              // done-counter (uint index)
#define WS_G     136                              // g[N_PROT]
#define WS_P     (WS_G + N_PROT)                  // P[N_PROT]

#define PB 1563                                   // 1563*32 = 50016 >= 50000 rows
#define SB 64                                     // sub-copy blocks
#define NBLK (PB + SB)
#define WBLK ((NWIN + 1023) / 1024)               // 49 window blocks (1024 thr)

typedef float v4f __attribute__((ext_vector_type(4)));

// =================== K1: stream prot->out + g/P; sub-copy ====================
// u1/u2 computed REDUNDANTLY per stream block (kills k_prep + its launch gap;
// Wp is 128 KB -> L2-resident per XCD, prologue overlaps the HBM stream).
__global__ __launch_bounds__(256) void k_main(
    const float* __restrict__ prot, const float* __restrict__ sub_node,
    const int* __restrict__ int_index, const float* __restrict__ Wp,
    const float* __restrict__ wa, float* __restrict__ out,
    float* __restrict__ ws) {
  const int tid = threadIdx.x, lane = tid & 63, wave = tid >> 6;
  const int b = blockIdx.x;
  if (b < PB) {
    // ---- prologue: u1[k] = Wp[k]·wa[:128], u2[k] = Wp[k]·1  (k = tid) ----
    __shared__ float swa[D_PROJ];
    __shared__ float su1[D_PROT], su2[D_PROT];
    if (tid < D_PROJ) swa[tid] = wa[tid];
    __syncthreads();
    {
      float s1 = 0.f, s2 = 0.f;
      const v4f* wrow = (const v4f*)&Wp[tid * D_PROJ];
      #pragma unroll 8
      for (int j4 = 0; j4 < D_PROJ / 4; ++j4) {
        v4f w = wrow[j4];
        v4f a = *(const v4f*)&swa[j4 * 4];
        s1 = fmaf(w.x, a.x, fmaf(w.y, a.y, fmaf(w.z, a.z, fmaf(w.w, a.w, s1))));
        s2 += w.x + w.y + w.z + w.w;
      }
      su1[tid] = s1; su2[tid] = s2;
    }
    __syncthreads();
    const v4f c1 = *(const v4f*)&su1[lane * 4];
    const v4f c2 = *(const v4f*)&su2[lane * 4];
    // ---- stream 32 rows: copy + g/P (plain stores, boundary-flushed) ----
    const int rbase = b * 32 + wave * 8;
    if (rbase + 8 <= N_PROT) {
      v4f av[8];
      #pragma unroll
      for (int i = 0; i < 8; ++i)
        av[i] = *(const v4f*)&prot[(rbase + i) * D_PROT + lane * 4];
      #pragma unroll
      for (int i = 0; i < 8; ++i)
        *(v4f*)&out[(rbase + i) * D_PROT + lane * 4] = av[i];
      #pragma unroll
      for (int i = 0; i < 8; ++i) {
        float g = av[i].x * c1.x + av[i].y * c1.y + av[i].z * c1.z + av[i].w * c1.w;
        float p = av[i].x * c2.x + av[i].y * c2.y + av[i].z * c2.z + av[i].w * c2.w;
        #pragma unroll
        for (int off = 32; off > 0; off >>= 1) {
          g += __shfl_xor(g, off, 64);
          p += __shfl_xor(p, off, 64);
        }
        if (lane == 0) {
          const int r = rbase + i;
          ws[WS_G + r] = g; ws[WS_P + r] = p;
        }
      }
    } else {
      for (int i = 0; i < 8; ++i) {
        const int r = rbase + i;
        if (r >= N_PROT) break;
        const v4f av = *(const v4f*)&prot[r * D_PROT + lane * 4];
        *(v4f*)&out[r * D_PROT + lane * 4] = av;
        float g = av.x * c1.x + av.y * c1.y + av.z * c1.z + av.w * c1.w;
        float p = av.x * c2.x + av.y * c2.y + av.z * c2.z + av.w * c2.w;
        for (int off = 32; off > 0; off >>= 1) {
          g += __shfl_xor(g, off, 64);
          p += __shfl_xor(p, off, 64);
        }
        if (lane == 0) { ws[WS_G + r] = g; ws[WS_P + r] = p; }
      }
    }
  } else {
    const int sb = b - PB;                        // 64 blocks, 2048 float4 each
    #pragma unroll
    for (int i = 0; i < 8; ++i) {
      const int gi = sb * 2048 + i * 256 + tid;
      if (gi < (N_SUB * D_SUB) / 4)
        *(v4f*)&out[OUT_SUB + gi * 4] = *(const v4f*)&sub_node[gi * 4];
    }
    if (sb == 0) {
      if (tid < N_INT) out[OUT_IDX + tid] = (float)int_index[tid];
      if (tid == 0) {
        *((unsigned long long*)ws) = 0ull;        // WS_PACK
        ((unsigned int*)ws)[WS_CNT] = 0u;         // ticket counter
      }
    }
  }
}

// =================== K2: window argmax + last-block parallel patch ===========
// reaction computed REDUNDANTLY per block in the prologue (kills the other
// half of k_prep); everything else is the baseline-proven structure.
__global__ __launch_bounds__(1024) void k_finish(
    const float* __restrict__ prot, const float* __restrict__ sub_node,
    const int* __restrict__ int_index, const float* __restrict__ Wp,
    const float* __restrict__ bp, const float* __restrict__ Ws,
    const float* __restrict__ bs, const float* __restrict__ sub_out,
    const float* __restrict__ prot_out, float* __restrict__ ws,
    float* __restrict__ out) {
  __shared__ float sg[1024 + KW], sp[1024 + KW];
  __shared__ unsigned long long wred[16];
  __shared__ int slast;
  __shared__ int   sidx[N_INT];
  __shared__ float ssum[D_SUB];
  __shared__ float rpart[8][D_PROJ];
  __shared__ float sreact[D_PROJ];
  const int tid = threadIdx.x;

  // ---- prologue: reaction[j] = 64*bs[j] + sum_d ssum[d]*Ws[d][j] ----
  if (tid < N_INT) sidx[tid] = int_index[tid];
  __syncthreads();
  if (tid < D_SUB) {
    float acc = 0.f;
    #pragma unroll 8
    for (int i = 0; i < N_INT; ++i) acc += sub_node[sidx[i] * D_SUB + tid];
    ssum[tid] = acc;
  }
  __syncthreads();
  {
    const int j = tid & 127, sl = tid >> 7;       // 8 slices x 32 d
    float p = 0.f;
    const float* wsp = Ws + (sl * 32) * D_PROJ + j;
    #pragma unroll 8
    for (int d = 0; d < 32; ++d) p = fmaf(ssum[sl * 32 + d], wsp[d * D_PROJ], p);
    rpart[sl][j] = p;
  }
  __syncthreads();
  if (tid < D_PROJ) {
    float r = 64.0f * bs[tid];
    #pragma unroll
    for (int s = 0; s < 8; ++s) r += rpart[s][tid];
    sreact[tid] = r;
  }

  // ---- window argmax over this block's 1024 windows ----
  const int w0 = blockIdx.x * 1024;
  for (int i = tid; i < 1024 + KW - 1; i += 1024) {
    int idx = w0 + i;
    bool ok = idx < N_PROT;
    sg[i] = ok ? ws[WS_G + idx] : -1e30f;
    sp[i] = ok ? ws[WS_P + idx] : 0.f;
  }
  __syncthreads();
  {
    int w = w0 + tid;
    unsigned long long best = 0ull;
    if (w < NWIN) {
      float m = sg[tid];
      #pragma unroll
      for (int k = 1; k < KW; ++k) m = fmaxf(m, sg[tid + k]);
      float s = 0.f, t = 0.f;
      #pragma unroll
      for (int k = 0; k < KW; ++k) {
        float e = expf(sg[tid + k] - m);
        s += e;
        t = fmaf(e, sp[tid + k], t);
      }
      t /= s;   // + const dropped: argmax-invariant
      unsigned int bb = __float_as_uint(t);
      unsigned int u = bb ^ ((bb & 0x80000000u) ? 0xFFFFFFFFu : 0x80000000u);
      best = ((unsigned long long)u << 32) |
             (unsigned long long)(0xFFFFFFFFu - (unsigned)w);
    }
    #pragma unroll
    for (int off = 32; off > 0; off >>= 1) {
      unsigned long long o = __shfl_xor(best, off, 64);
      if (o > best) best = o;
    }
    if ((tid & 63) == 0) wred[tid >> 6] = best;
  }
  __syncthreads();
  if (tid == 0) {
    unsigned long long b2 = wred[0];
    for (int i = 1; i < 16; ++i) if (wred[i] > b2) b2 = wred[i];
    atomicMax((unsigned long long*)ws, b2);
    __threadfence();                               // release my atomicMax
    unsigned int ticket = atomicAdd(&((unsigned int*)ws)[WS_CNT], 1u);
    slast = (ticket == WBLK - 1) ? 1 : 0;
  }
  __syncthreads();
  if (!slast) return;

  // -------- last block (1024 thr): all atomicMax's globally visible ----------
  __shared__ float aprot[KW][D_PROT];              // 16 KB
  __shared__ float attn[KW];
  __shared__ float v[D_PROT];                      // attn-weighted window row
  __shared__ float part[8][D_PROJ];                // ts partials
  __shared__ float ts[D_PROJ];
  __shared__ float partP[4][D_PROT], partS[4][D_PROT];
  __shared__ float pdelta[D_PROT], sdelta[D_SUB];
  __shared__ int   swtop;
  if (tid == 0) {
    unsigned long long pk = atomicMax((unsigned long long*)ws, 0ull);
    swtop = (int)(0xFFFFFFFFu - (unsigned)(pk & 0xFFFFFFFFull));
  }
  __syncthreads();
  const int wtop = swtop;
  {  // load the 16 window rows (1024 float4's, one per thread)
    const int row = tid >> 6, c4 = (tid & 63) * 4;
    *(v4f*)&aprot[row][c4] = *(const v4f*)&prot[(wtop + row) * D_PROT + c4];
  }
  if (tid == 0) {   // softmax over g window (shift-invariant vs ref)
    float m = ws[WS_G + wtop];
    for (int k = 1; k < KW; ++k) m = fmaxf(m, ws[WS_G + wtop + k]);
    float e[KW], s = 0.f;
    for (int k = 0; k < KW; ++k) { e[k] = expf(ws[WS_G + wtop + k] - m); s += e[k]; }
    for (int k = 0; k < KW; ++k) attn[k] = e[k] / s;
  }
  __syncthreads();
  if (tid < D_PROT) {  // v = attn @ A_window  (exploits sum(attn)=1 for bp term)
    float a = 0.f;
    #pragma unroll
    for (int k = 0; k < KW; ++k) a = fmaf(attn[k], aprot[k][tid], a);
    v[tid] = a;
  }
  __syncthreads();
  {  // ts partials: ts[j] = react[j] + bp[j] + sum_d v[d]*Wp[d][j]
    const int j = tid & 127, s = tid >> 7;        // 8 slices x 32 d
    float p = 0.f;
    const float* wp = Wp + (s * 32) * D_PROJ + j;
    #pragma unroll 8
    for (int d = 0; d < 32; ++d) p = fmaf(v[s * 32 + d], wp[d * D_PROJ], p);
    part[s][j] = p;
  }
  __syncthreads();
  if (tid < D_PROJ) {
    float a = sreact[tid] + bp[tid];
    #pragma unroll
    for (int s = 0; s < 8; ++s) a += part[s][tid];
    ts[tid] = a;
  }
  __syncthreads();
  {  // pdelta/sdelta partials: 4 slices x 32 j each, coalesced over d
    const int d = tid & 255, s = tid >> 8;
    float pp = 0.f, ss = 0.f;
    #pragma unroll 8
    for (int j = 0; j < 32; ++j) {
      const float t = ts[s * 32 + j];
      pp = fmaf(t, prot_out[(s * 32 + j) * D_PROT + d], pp);
      ss = fmaf(t, sub_out[(s * 32 + j) * D_SUB + d], ss);
    }
    partP[s][d] = pp; partS[s][d] = ss;
  }
  __syncthreads();
  if (tid < D_PROT) {
    pdelta[tid] = partP[0][tid] + partP[1][tid] + partP[2][tid] + partP[3][tid];
    sdelta[tid] = partS[0][tid] + partS[1][tid] + partS[2][tid] + partS[3][tid];
  }
  __syncthreads();
  {  // write 16 prot rows
    const int row = tid >> 6, c4 = (tid & 63) * 4;
    v4f a = *(v4f*)&aprot[row][c4];
    v4f d = *(v4f*)&pdelta[c4];
    a.x += d.x; a.y += d.y; a.z += d.z; a.w += d.w;
    *(v4f*)&out[(wtop + row) * D_PROT + c4] = a;
  }
  #pragma unroll
  for (int it = 0; it < 4; ++it) {  // write 64 sub rows (dups: same value)
    const int f = tid + it * 1024;                // 4096 float4 over 64 rows
    const int row = f >> 6, c4 = (f & 63) * 4;
    const int rr = sidx[row];
    v4f sv = *(const v4f*)&sub_node[rr * D_SUB + c4];
    v4f d = *(v4f*)&sdelta[c4];
    sv.x += d.x; sv.y += d.y; sv.z += d.z; sv.w += d.w;
    *(v4f*)&out[OUT_SUB + rr * D_SUB + c4] = sv;
  }
}

extern "C" void kernel_launch(void* const* d_in, const int* in_sizes, int n_in,
                              void* d_out, int out_size, void* d_ws, size_t ws_size,
                              hipStream_t stream) {
  const float* prot     = (const float*)d_in[0];
  const float* sub      = (const float*)d_in[1];
  const int*   idx      = (const int*)d_in[2];
  const float* Wp       = (const float*)d_in[3];
  const float* bp       = (const float*)d_in[4];
  const float* Ws       = (const float*)d_in[5];
  const float* bs       = (const float*)d_in[6];
  const float* wa       = (const float*)d_in[7];
  // d_in[8] = ba unused (cancels in softmax); wa[128:] unused (constant in g)
  const float* sub_out  = (const float*)d_in[9];
  const float* prot_out = (const float*)d_in[10];
  float* out = (float*)d_out;
  float* ws  = (float*)d_ws;

  k_main<<<NBLK, 256, 0, stream>>>(prot, sub, idx, Wp, wa, out, ws);
  k_finish<<<WBLK, 1024, 0, stream>>>(prot, sub, idx, Wp, bp, Ws, bs,
                                      sub_out, prot_out, ws, out);
}

// Round 5
// 151.367 us; speedup vs baseline: 1.4660x; 1.0621x over previous
//
#include <hip/hip_runtime.h>
#include <math.h>

#define N_PROT 50000
#define N_SUB  2000
#define D_PROT 256
#define D_SUB  256
#define D_PROJ 128
#define KW     16
#define N_INT  64
#define NWIN   (N_PROT - KW + 1)

// output layout (floats)
#define OUT_SUB (N_PROT * D_PROT)                 // 12,800,000
#define OUT_IDX (OUT_SUB + N_SUB * D_SUB)         // 13,312,000

// ws layout (floats)
#define WS_PACK  0                                // [0..1] packed argmax u64
#define WS_REACT 2                                // [2..129] reaction
#define WS_CNT   130                              // done-counter (uint)
#define WS_U1    132                              // u1 = Wp @ w1 (256)
#define WS_U2    388                              // u2 = Wp @ ones (256)
#define WS_G     644                              // g[N_PROT] (no constant term)
#define WS_P     (WS_G + N_PROT)                  // P[N_PROT] (no constant term)

#define PB 1563                                   // 1563*32 = 50016 >= 50000 rows
#define SB 64                                     // sub-copy blocks
#define NBLK (PB + SB)
#define WBLK ((NWIN + 1023) / 1024)               // 49 window blocks (1024 thr)

// ---- wave64 sum via DPP (VALU pipe only, no DS ops). Result in lane 63. ----
// Canonical GCN sequence: row_shr 1/2/4/8 (intra-16 suffix) + row_bcast 15/31.
__device__ __forceinline__ float wave_sum64(float x) {
  int v;
  v = __builtin_amdgcn_update_dpp(0, __float_as_int(x), 0x111, 0xf, 0xf, true);
  x += __int_as_float(v);                         // row_shr:1
  v = __builtin_amdgcn_update_dpp(0, __float_as_int(x), 0x112, 0xf, 0xf, true);
  x += __int_as_float(v);                         // row_shr:2
  v = __builtin_amdgcn_update_dpp(0, __float_as_int(x), 0x114, 0xf, 0xf, true);
  x += __int_as_float(v);                         // row_shr:4
  v = __builtin_amdgcn_update_dpp(0, __float_as_int(x), 0x118, 0xf, 0xf, true);
  x += __int_as_float(v);                         // row_shr:8  -> lane15 of each row = row sum
  v = __builtin_amdgcn_update_dpp(0, __float_as_int(x), 0x142, 0xf, 0xf, true);
  x += __int_as_float(v);                         // row_bcast:15 -> lane31 = rows0+1, lane63 = rows2+3
  v = __builtin_amdgcn_update_dpp(0, __float_as_int(x), 0x143, 0xf, 0xf, true);
  x += __int_as_float(v);                         // row_bcast:31 -> lane63 = full sum
  return x;
}

// =================== K0: reaction + u1/u2 + counters (2 blocks) ==============
__global__ __launch_bounds__(256) void k_prep(
    const float* __restrict__ sub_node, const int* __restrict__ int_index,
    const float* __restrict__ Ws, const float* __restrict__ bs,
    const float* __restrict__ Wp, const float* __restrict__ wa,
    float* __restrict__ ws) {
  const int tid = threadIdx.x;
  if (blockIdx.x == 0) {
    __shared__ int   sidx[N_INT];
    __shared__ float ssum[D_SUB];
    if (tid < N_INT) sidx[tid] = int_index[tid];
    __syncthreads();
    float acc = 0.f;
    #pragma unroll 8
    for (int i = 0; i < N_INT; ++i) acc += sub_node[sidx[i] * D_SUB + tid];
    ssum[tid] = acc;
    __syncthreads();
    if (tid < D_PROJ) {
      float r = 64.0f * bs[tid];
      #pragma unroll 8
      for (int d = 0; d < D_SUB; ++d) r = fmaf(ssum[d], Ws[d * D_PROJ + tid], r);
      ws[WS_REACT + tid] = r;
    }
    if (tid == 0) {
      *((unsigned long long*)ws) = 0ull;          // WS_PACK
      ((unsigned int*)ws)[WS_CNT] = 0u;           // done-counter
    }
  } else {
    // u1[k] = sum_j Wp[k][j] * wa[j];  u2[k] = sum_j Wp[k][j]
    __shared__ float swa[D_PROJ];
    if (tid < D_PROJ) swa[tid] = wa[tid];
    __syncthreads();
    float s1 = 0.f, s2 = 0.f;
    const float4* wrow = (const float4*)&Wp[tid * D_PROJ];
    #pragma unroll 8
    for (int j4 = 0; j4 < D_PROJ / 4; ++j4) {
      float4 w = wrow[j4];
      float4 a = *(const float4*)&swa[j4 * 4];
      s1 = fmaf(w.x, a.x, fmaf(w.y, a.y, fmaf(w.z, a.z, fmaf(w.w, a.w, s1))));
      s2 += w.x + w.y + w.z + w.w;
    }
    ws[WS_U1 + tid] = s1;
    ws[WS_U2 + tid] = s2;
  }
}

// =================== K1: stream prot->out + g/P; sub-copy ====================
__global__ __launch_bounds__(256) void k_main(
    const float* __restrict__ prot, const float* __restrict__ sub_node,
    const int* __restrict__ int_index, float* __restrict__ out,
    float* __restrict__ ws) {
  const int tid = threadIdx.x, lane = tid & 63, wave = tid >> 6;
  const int b = blockIdx.x;
  if (b < PB) {
    const float4 c1 = *(const float4*)&ws[WS_U1 + lane * 4];
    const float4 c2 = *(const float4*)&ws[WS_U2 + lane * 4];
    const int rbase = b * 32 + wave * 8;
    if (rbase + 8 <= N_PROT) {
      float4 av[8];
      #pragma unroll
      for (int i = 0; i < 8; ++i)
        av[i] = *(const float4*)&prot[(rbase + i) * D_PROT + lane * 4];
      #pragma unroll
      for (int i = 0; i < 8; ++i)
        *(float4*)&out[(rbase + i) * D_PROT + lane * 4] = av[i];
      #pragma unroll
      for (int i = 0; i < 8; ++i) {
        float g = av[i].x * c1.x + av[i].y * c1.y + av[i].z * c1.z + av[i].w * c1.w;
        float p = av[i].x * c2.x + av[i].y * c2.y + av[i].z * c2.z + av[i].w * c2.w;
        g = wave_sum64(g);
        p = wave_sum64(p);
        if (lane == 63) {
          const int r = rbase + i;
          ws[WS_G + r] = g; ws[WS_P + r] = p;
        }
      }
    } else {
      for (int i = 0; i < 8; ++i) {
        const int r = rbase + i;
        if (r >= N_PROT) break;
        const float4 av = *(const float4*)&prot[r * D_PROT + lane * 4];
        *(float4*)&out[r * D_PROT + lane * 4] = av;
        float g = av.x * c1.x + av.y * c1.y + av.z * c1.z + av.w * c1.w;
        float p = av.x * c2.x + av.y * c2.y + av.z * c2.z + av.w * c2.w;
        g = wave_sum64(g);
        p = wave_sum64(p);
        if (lane == 63) { ws[WS_G + r] = g; ws[WS_P + r] = p; }
      }
    }
  } else {
    const int sb = b - PB;                        // 64 blocks, 2048 float4 each
    #pragma unroll
    for (int i = 0; i < 8; ++i) {
      const int gi = sb * 2048 + i * 256 + tid;
      if (gi < (N_SUB * D_SUB) / 4)
        *(float4*)&out[OUT_SUB + gi * 4] = *(const float4*)&sub_node[gi * 4];
    }
    if (sb == 0 && tid < N_INT) out[OUT_IDX + tid] = (float)int_index[tid];
  }
}

// =================== K2: window argmax + last-block parallel patch ===========
__global__ __launch_bounds__(1024) void k_finish(
    const float* __restrict__ prot, const float* __restrict__ sub_node,
    const int* __restrict__ int_index, const float* __restrict__ Wp,
    const float* __restrict__ bp, const float* __restrict__ sub_out,
    const float* __restrict__ prot_out, float* __restrict__ ws,
    float* __restrict__ out) {
  __shared__ float sg[1024 + KW], sp[1024 + KW];
  __shared__ unsigned long long wred[16];
  __shared__ int slast;
  const int tid = threadIdx.x;
  const int w0 = blockIdx.x * 1024;
  for (int i = tid; i < 1024 + KW - 1; i += 1024) {
    int idx = w0 + i;
    bool ok = idx < N_PROT;
    sg[i] = ok ? ws[WS_G + idx] : -1e30f;
    sp[i] = ok ? ws[WS_P + idx] : 0.f;
  }
  __syncthreads();
  {
    int w = w0 + tid;
    unsigned long long best = 0ull;
    if (w < NWIN) {
      float m = sg[tid];
      #pragma unroll
      for (int k = 1; k < KW; ++k) m = fmaxf(m, sg[tid + k]);
      float s = 0.f, t = 0.f;
      #pragma unroll
      for (int k = 0; k < KW; ++k) {
        float e = expf(sg[tid + k] - m);
        s += e;
        t = fmaf(e, sp[tid + k], t);
      }
      t /= s;   // + const dropped: argmax-invariant
      unsigned int bb = __float_as_uint(t);
      unsigned int u = bb ^ ((bb & 0x80000000u) ? 0xFFFFFFFFu : 0x80000000u);
      best = ((unsigned long long)u << 32) |
             (unsigned long long)(0xFFFFFFFFu - (unsigned)w);
    }
    #pragma unroll
    for (int off = 32; off > 0; off >>= 1) {
      unsigned long long o = __shfl_xor(best, off, 64);
      if (o > best) best = o;
    }
    if ((tid & 63) == 0) wred[tid >> 6] = best;
  }
  __syncthreads();
  if (tid == 0) {
    unsigned long long b2 = wred[0];
    for (int i = 1; i < 16; ++i) if (wred[i] > b2) b2 = wred[i];
    atomicMax((unsigned long long*)ws, b2);
    __threadfence();                               // release my atomicMax
    unsigned int ticket = atomicAdd(&((unsigned int*)ws)[WS_CNT], 1u);
    slast = (ticket == WBLK - 1) ? 1 : 0;
  }
  __syncthreads();
  if (!slast) return;

  // -------- last block (1024 thr): all atomicMax's globally visible ----------
  __shared__ float aprot[KW][D_PROT];              // 16 KB
  __shared__ float attn[KW];
  __shared__ float v[D_PROT];                      // attn-weighted window row
  __shared__ float part[8][D_PROJ];                // ts partials
  __shared__ float ts[D_PROJ];
  __shared__ float partP[4][D_PROT], partS[4][D_PROT];
  __shared__ float pdelta[D_PROT], sdelta[D_SUB];
  __shared__ int   sidx[N_INT];
  __shared__ int   swtop;
  if (tid == 0) {
    unsigned long long pk = atomicMax((unsigned long long*)ws, 0ull);
    swtop = (int)(0xFFFFFFFFu - (unsigned)(pk & 0xFFFFFFFFull));
  }
  __syncthreads();
  const int wtop = swtop;
  {  // load the 16 window rows (1024 float4's, one per thread)
    const int row = tid >> 6, c4 = (tid & 63) * 4;
    *(float4*)&aprot[row][c4] = *(const float4*)&prot[(wtop + row) * D_PROT + c4];
  }
  if (tid < N_INT) sidx[tid] = int_index[tid];
  if (tid == 0) {   // softmax over g window (shift-invariant vs ref)
    float m = ws[WS_G + wtop];
    for (int k = 1; k < KW; ++k) m = fmaxf(m, ws[WS_G + wtop + k]);
    float e[KW], s = 0.f;
    for (int k = 0; k < KW; ++k) { e[k] = expf(ws[WS_G + wtop + k] - m); s += e[k]; }
    for (int k = 0; k < KW; ++k) attn[k] = e[k] / s;
  }
  __syncthreads();
  if (tid < D_PROT) {  // v = attn @ A_window  (exploits sum(attn)=1 for bp term)
    float a = 0.f;
    #pragma unroll
    for (int k = 0; k < KW; ++k) a = fmaf(attn[k], aprot[k][tid], a);
    v[tid] = a;
  }
  __syncthreads();
  {  // ts partials: ts[j] = react[j] + bp[j] + sum_d v[d]*Wp[d][j]
    const int j = tid & 127, s = tid >> 7;        // 8 slices x 32 d
    float p = 0.f;
    const float* wp = Wp + (s * 32) * D_PROJ + j;
    #pragma unroll 8
    for (int d = 0; d < 32; ++d) p = fmaf(v[s * 32 + d], wp[d * D_PROJ], p);
    part[s][j] = p;
  }
  __syncthreads();
  if (tid < D_PROJ) {
    float a = ws[WS_REACT + tid] + bp[tid];
    #pragma unroll
    for (int s = 0; s < 8; ++s) a += part[s][tid];
    ts[tid] = a;
  }
  __syncthreads();
  {  // pdelta/sdelta partials: 4 slices x 32 j each, coalesced over d
    const int d = tid & 255, s = tid >> 8;
    float pp = 0.f, ss = 0.f;
    #pragma unroll 8
    for (int j = 0; j < 32; ++j) {
      const float t = ts[s * 32 + j];
      pp = fmaf(t, prot_out[(s * 32 + j) * D_PROT + d], pp);
      ss = fmaf(t, sub_out[(s * 32 + j) * D_SUB + d], ss);
    }
    partP[s][d] = pp; partS[s][d] = ss;
  }
  __syncthreads();
  if (tid < D_PROT) {
    pdelta[tid] = partP[0][tid] + partP[1][tid] + partP[2][tid] + partP[3][tid];
    sdelta[tid] = partS[0][tid] + partS[1][tid] + partS[2][tid] + partS[3][tid];
  }
  __syncthreads();
  {  // write 16 prot rows
    const int row = tid >> 6, c4 = (tid & 63) * 4;
    float4 a = *(float4*)&aprot[row][c4];
    float4 d = *(float4*)&pdelta[c4];
    a.x += d.x; a.y += d.y; a.z += d.z; a.w += d.w;
    *(float4*)&out[(wtop + row) * D_PROT + c4] = a;
  }
  #pragma unroll
  for (int it = 0; it < 4; ++it) {  // write 64 sub rows (dups: same value)
    const int f = tid + it * 1024;                // 4096 float4 over 64 rows
    const int row = f >> 6, c4 = (f & 63) * 4;
    const int rr = sidx[row];
    float4 sv = *(const float4*)&sub_node[rr * D_SUB + c4];
    float4 d = *(float4*)&sdelta[c4];
    sv.x += d.x; sv.y += d.y; sv.z += d.z; sv.w += d.w;
    *(float4*)&out[OUT_SUB + rr * D_SUB + c4] = sv;
  }
}

extern "C" void kernel_launch(void* const* d_in, const int* in_sizes, int n_in,
                              void* d_out, int out_size, void* d_ws, size_t ws_size,
                              hipStream_t stream) {
  const float* prot     = (const float*)d_in[0];
  const float* sub      = (const float*)d_in[1];
  const int*   idx      = (const int*)d_in[2];
  const float* Wp       = (const float*)d_in[3];
  const float* bp       = (const float*)d_in[4];
  const float* Ws       = (const float*)d_in[5];
  const float* bs       = (const float*)d_in[6];
  const float* wa       = (const float*)d_in[7];
  // d_in[8] = ba unused (cancels in softmax); wa[128:] unused (constant in g)
  const float* sub_out  = (const float*)d_in[9];
  const float* prot_out = (const float*)d_in[10];
  float* out = (float*)d_out;
  float* ws  = (float*)d_ws;

  k_prep<<<2, 256, 0, stream>>>(sub, idx, Ws, bs, Wp, wa, ws);
  k_main<<<NBLK, 256, 0, stream>>>(prot, sub, idx, out, ws);
  k_finish<<<WBLK, 1024, 0, stream>>>(prot, sub, idx, Wp, bp, sub_out, prot_out,
                                      ws, out);
}

// Round 6
// 151.064 us; speedup vs baseline: 1.4689x; 1.0020x over previous
//
#include <hip/hip_runtime.h>
#include <math.h>

#define N_PROT 50000
#define N_SUB  2000
#define D_PROT 256
#define D_SUB  256
#define D_PROJ 128
#define KW     16
#define N_INT  64
#define NWIN   (N_PROT - KW + 1)

// output layout (floats)
#define OUT_SUB (N_PROT * D_PROT)                 // 12,800,000
#define OUT_IDX (OUT_SUB + N_SUB * D_SUB)         // 13,312,000

// ws layout (floats)
#define WS_PACK  0                                // [0..1] packed argmax u64
#define WS_REACT 2                                // [2..129] reaction
#define WS_CNT   130                              // done-counter (uint)
#define WS_U1    132                              // u1 = Wp @ w1 (256)
#define WS_U2    388                              // u2 = Wp @ ones (256)
#define WS_G     644                              // g[N_PROT] (no constant term)
#define WS_P     (WS_G + N_PROT)                  // P[N_PROT] (no constant term)

#define PB 1563                                   // 1563*32 = 50016 >= 50000 rows
#define SB 64                                     // sub-copy blocks
#define NBLK (PB + SB)
#define WBLK ((NWIN + 1023) / 1024)               // 49 window blocks (1024 thr)

// ---- wave64 sum via DPP (VALU pipe only, no DS ops). Result in lane 63. ----
__device__ __forceinline__ float wave_sum64(float x) {
  int v;
  v = __builtin_amdgcn_update_dpp(0, __float_as_int(x), 0x111, 0xf, 0xf, true);
  x += __int_as_float(v);                         // row_shr:1
  v = __builtin_amdgcn_update_dpp(0, __float_as_int(x), 0x112, 0xf, 0xf, true);
  x += __int_as_float(v);                         // row_shr:2
  v = __builtin_amdgcn_update_dpp(0, __float_as_int(x), 0x114, 0xf, 0xf, true);
  x += __int_as_float(v);                         // row_shr:4
  v = __builtin_amdgcn_update_dpp(0, __float_as_int(x), 0x118, 0xf, 0xf, true);
  x += __int_as_float(v);                         // row_shr:8
  v = __builtin_amdgcn_update_dpp(0, __float_as_int(x), 0x142, 0xf, 0xf, true);
  x += __int_as_float(v);                         // row_bcast:15
  v = __builtin_amdgcn_update_dpp(0, __float_as_int(x), 0x143, 0xf, 0xf, true);
  x += __int_as_float(v);                         // row_bcast:31 -> lane63 = full sum
  return x;
}

// =================== K0: reaction + u1/u2 + counters (2 blocks) ==============
__global__ __launch_bounds__(256) void k_prep(
    const float* __restrict__ sub_node, const int* __restrict__ int_index,
    const float* __restrict__ Ws, const float* __restrict__ bs,
    const float* __restrict__ Wp, const float* __restrict__ wa,
    float* __restrict__ ws) {
  const int tid = threadIdx.x;
  if (blockIdx.x == 0) {
    __shared__ int   sidx[N_INT];
    __shared__ float ssum[D_SUB];
    if (tid < N_INT) sidx[tid] = int_index[tid];
    __syncthreads();
    float acc = 0.f;
    #pragma unroll 8
    for (int i = 0; i < N_INT; ++i) acc += sub_node[sidx[i] * D_SUB + tid];
    ssum[tid] = acc;
    __syncthreads();
    if (tid < D_PROJ) {
      float r = 64.0f * bs[tid];
      #pragma unroll 8
      for (int d = 0; d < D_SUB; ++d) r = fmaf(ssum[d], Ws[d * D_PROJ + tid], r);
      ws[WS_REACT + tid] = r;
    }
    if (tid == 0) {
      *((unsigned long long*)ws) = 0ull;          // WS_PACK
      ((unsigned int*)ws)[WS_CNT] = 0u;           // done-counter
    }
  } else {
    // u1[k] = sum_j Wp[k][j] * wa[j];  u2[k] = sum_j Wp[k][j]
    __shared__ float swa[D_PROJ];
    if (tid < D_PROJ) swa[tid] = wa[tid];
    __syncthreads();
    float s1 = 0.f, s2 = 0.f;
    const float4* wrow = (const float4*)&Wp[tid * D_PROJ];
    #pragma unroll 8
    for (int j4 = 0; j4 < D_PROJ / 4; ++j4) {
      float4 w = wrow[j4];
      float4 a = *(const float4*)&swa[j4 * 4];
      s1 = fmaf(w.x, a.x, fmaf(w.y, a.y, fmaf(w.z, a.z, fmaf(w.w, a.w, s1))));
      s2 += w.x + w.y + w.z + w.w;
    }
    ws[WS_U1 + tid] = s1;
    ws[WS_U2 + tid] = s2;
  }
}

// =================== K1: stream prot->out + g/P; sub-copy ====================
// __launch_bounds__(256, 4): cap occupancy at 4 blocks/CU (16 waves/CU, all
// the work-limited grid can use) -> VGPR budget 128, so the 8 float4 loads
// stay live and 8-deep in flight instead of serialized into a 32-VGPR frame.
__global__ __launch_bounds__(256, 4) void k_main(
    const float* __restrict__ prot, const float* __restrict__ sub_node,
    const int* __restrict__ int_index, float* __restrict__ out,
    float* __restrict__ ws) {
  const int tid = threadIdx.x, lane = tid & 63, wave = tid >> 6;
  const int b = blockIdx.x;
  if (b < PB) {
    const float4 c1 = *(const float4*)&ws[WS_U1 + lane * 4];
    const float4 c2 = *(const float4*)&ws[WS_U2 + lane * 4];
    const int rbase = b * 32 + wave * 8;
    if (rbase + 8 <= N_PROT) {
      float4 av[8];
      #pragma unroll
      for (int i = 0; i < 8; ++i)
        av[i] = *(const float4*)&prot[(rbase + i) * D_PROT + lane * 4];
      #pragma unroll
      for (int i = 0; i < 8; ++i)
        *(float4*)&out[(rbase + i) * D_PROT + lane * 4] = av[i];
      #pragma unroll
      for (int i = 0; i < 8; ++i) {
        float g = av[i].x * c1.x + av[i].y * c1.y + av[i].z * c1.z + av[i].w * c1.w;
        float p = av[i].x * c2.x + av[i].y * c2.y + av[i].z * c2.z + av[i].w * c2.w;
        g = wave_sum64(g);
        p = wave_sum64(p);
        if (lane == 63) {
          const int r = rbase + i;
          ws[WS_G + r] = g; ws[WS_P + r] = p;
        }
      }
    } else {
      for (int i = 0; i < 8; ++i) {
        const int r = rbase + i;
        if (r >= N_PROT) break;
        const float4 av = *(const float4*)&prot[r * D_PROT + lane * 4];
        *(float4*)&out[r * D_PROT + lane * 4] = av;
        float g = av.x * c1.x + av.y * c1.y + av.z * c1.z + av.w * c1.w;
        float p = av.x * c2.x + av.y * c2.y + av.z * c2.z + av.w * c2.w;
        g = wave_sum64(g);
        p = wave_sum64(p);
        if (lane == 63) { ws[WS_G + r] = g; ws[WS_P + r] = p; }
      }
    }
  } else {
    const int sb = b - PB;                        // 64 blocks, 2048 float4 each
    #pragma unroll
    for (int i = 0; i < 8; ++i) {
      const int gi = sb * 2048 + i * 256 + tid;
      if (gi < (N_SUB * D_SUB) / 4)
        *(float4*)&out[OUT_SUB + gi * 4] = *(const float4*)&sub_node[gi * 4];
    }
    if (sb == 0 && tid < N_INT) out[OUT_IDX + tid] = (float)int_index[tid];
  }
}

// =================== K2: window argmax + last-block parallel patch ===========
__global__ __launch_bounds__(1024) void k_finish(
    const float* __restrict__ prot, const float* __restrict__ sub_node,
    const int* __restrict__ int_index, const float* __restrict__ Wp,
    const float* __restrict__ bp, const float* __restrict__ sub_out,
    const float* __restrict__ prot_out, float* __restrict__ ws,
    float* __restrict__ out) {
  __shared__ float sg[1024 + KW], sp[1024 + KW];
  __shared__ unsigned long long wred[16];
  __shared__ int slast;
  const int tid = threadIdx.x;
  const int w0 = blockIdx.x * 1024;
  for (int i = tid; i < 1024 + KW - 1; i += 1024) {
    int idx = w0 + i;
    bool ok = idx < N_PROT;
    sg[i] = ok ? ws[WS_G + idx] : -1e30f;
    sp[i] = ok ? ws[WS_P + idx] : 0.f;
  }
  __syncthreads();
  {
    int w = w0 + tid;
    unsigned long long best = 0ull;
    if (w < NWIN) {
      float m = sg[tid];
      #pragma unroll
      for (int k = 1; k < KW; ++k) m = fmaxf(m, sg[tid + k]);
      float s = 0.f, t = 0.f;
      #pragma unroll
      for (int k = 0; k < KW; ++k) {
        float e = expf(sg[tid + k] - m);
        s += e;
        t = fmaf(e, sp[tid + k], t);
      }
      t /= s;   // + const dropped: argmax-invariant
      unsigned int bb = __float_as_uint(t);
      unsigned int u = bb ^ ((bb & 0x80000000u) ? 0xFFFFFFFFu : 0x80000000u);
      best = ((unsigned long long)u << 32) |
             (unsigned long long)(0xFFFFFFFFu - (unsigned)w);
    }
    #pragma unroll
    for (int off = 32; off > 0; off >>= 1) {
      unsigned long long o = __shfl_xor(best, off, 64);
      if (o > best) best = o;
    }
    if ((tid & 63) == 0) wred[tid >> 6] = best;
  }
  __syncthreads();
  if (tid == 0) {
    unsigned long long b2 = wred[0];
    for (int i = 1; i < 16; ++i) if (wred[i] > b2) b2 = wred[i];
    atomicMax((unsigned long long*)ws, b2);
    __threadfence();                               // release my atomicMax
    unsigned int ticket = atomicAdd(&((unsigned int*)ws)[WS_CNT], 1u);
    slast = (ticket == WBLK - 1) ? 1 : 0;
  }
  __syncthreads();
  if (!slast) return;

  // -------- last block (1024 thr): all atomicMax's globally visible ----------
  __shared__ float aprot[KW][D_PROT];              // 16 KB
  __shared__ float attn[KW];
  __shared__ float v[D_PROT];                      // attn-weighted window row
  __shared__ float part[8][D_PROJ];                // ts partials
  __shared__ float ts[D_PROJ];
  __shared__ float partP[4][D_PROT], partS[4][D_PROT];
  __shared__ float pdelta[D_PROT], sdelta[D_SUB];
  __shared__ int   sidx[N_INT];
  __shared__ int   swtop;
  if (tid == 0) {
    unsigned long long pk = atomicMax((unsigned long long*)ws, 0ull);
    swtop = (int)(0xFFFFFFFFu - (unsigned)(pk & 0xFFFFFFFFull));
  }
  __syncthreads();
  const int wtop = swtop;
  {  // load the 16 window rows (1024 float4's, one per thread)
    const int row = tid >> 6, c4 = (tid & 63) * 4;
    *(float4*)&aprot[row][c4] = *(const float4*)&prot[(wtop + row) * D_PROT + c4];
  }
  if (tid < N_INT) sidx[tid] = int_index[tid];
  if (tid == 0) {   // softmax over g window (shift-invariant vs ref)
    float m = ws[WS_G + wtop];
    for (int k = 1; k < KW; ++k) m = fmaxf(m, ws[WS_G + wtop + k]);
    float e[KW], s = 0.f;
    for (int k = 0; k < KW; ++k) { e[k] = expf(ws[WS_G + wtop + k] - m); s += e[k]; }
    for (int k = 0; k < KW; ++k) attn[k] = e[k] / s;
  }
  __syncthreads();
  if (tid < D_PROT) {  // v = attn @ A_window  (exploits sum(attn)=1 for bp term)
    float a = 0.f;
    #pragma unroll
    for (int k = 0; k < KW; ++k) a = fmaf(attn[k], aprot[k][tid], a);
    v[tid] = a;
  }
  __syncthreads();
  {  // ts partials: ts[j] = react[j] + bp[j] + sum_d v[d]*Wp[d][j]
    const int j = tid & 127, s = tid >> 7;        // 8 slices x 32 d
    float p = 0.f;
    const float* wp = Wp + (s * 32) * D_PROJ + j;
    #pragma unroll 8
    for (int d = 0; d < 32; ++d) p = fmaf(v[s * 32 + d], wp[d * D_PROJ], p);
    part[s][j] = p;
  }
  __syncthreads();
  if (tid < D_PROJ) {
    float a = ws[WS_REACT + tid] + bp[tid];
    #pragma unroll
    for (int s = 0; s < 8; ++s) a += part[s][tid];
    ts[tid] = a;
  }
  __syncthreads();
  {  // pdelta/sdelta partials: 4 slices x 32 j each, coalesced over d
    const int d = tid & 255, s = tid >> 8;
    float pp = 0.f, ss = 0.f;
    #pragma unroll 8
    for (int j = 0; j < 32; ++j) {
      const float t = ts[s * 32 + j];
      pp = fmaf(t, prot_out[(s * 32 + j) * D_PROT + d], pp);
      ss = fmaf(t, sub_out[(s * 32 + j) * D_SUB + d], ss);
    }
    partP[s][d] = pp; partS[s][d] = ss;
  }
  __syncthreads();
  if (tid < D_PROT) {
    pdelta[tid] = partP[0][tid] + partP[1][tid] + partP[2][tid] + partP[3][tid];
    sdelta[tid] = partS[0][tid] + partS[1][tid] + partS[2][tid] + partS[3][tid];
  }
  __syncthreads();
  {  // write 16 prot rows
    const int row = tid >> 6, c4 = (tid & 63) * 4;
    float4 a = *(float4*)&aprot[row][c4];
    float4 d = *(float4*)&pdelta[c4];
    a.x += d.x; a.y += d.y; a.z += d.z; a.w += d.w;
    *(float4*)&out[(wtop + row) * D_PROT + c4] = a;
  }
  #pragma unroll
  for (int it = 0; it < 4; ++it) {  // write 64 sub rows (dups: same value)
    const int f = tid + it * 1024;                // 4096 float4 over 64 rows
    const int row = f >> 6, c4 = (f & 63) * 4;
    const int rr = sidx[row];
    float4 sv = *(const float4*)&sub_node[rr * D_SUB + c4];
    float4 d = *(float4*)&sdelta[c4];
    sv.x += d.x; sv.y += d.y; sv.z += d.z; sv.w += d.w;
    *(float4*)&out[OUT_SUB + rr * D_SUB + c4] = sv;
  }
}

extern "C" void kernel_launch(void* const* d_in, const int* in_sizes, int n_in,
                              void* d_out, int out_size, void* d_ws, size_t ws_size,
                              hipStream_t stream) {
  const float* prot     = (const float*)d_in[0];
  const float* sub      = (const float*)d_in[1];
  const int*   idx      = (const int*)d_in[2];
  const float* Wp       = (const float*)d_in[3];
  const float* bp       = (const float*)d_in[4];
  const float* Ws       = (const float*)d_in[5];
  const float* bs       = (const float*)d_in[6];
  const float* wa       = (const float*)d_in[7];
  // d_in[8] = ba unused (cancels in softmax); wa[128:] unused (constant in g)
  const float* sub_out  = (const float*)d_in[9];
  const float* prot_out = (const float*)d_in[10];
  float* out = (float*)d_out;
  float* ws  = (float*)d_ws;

  k_prep<<<2, 256, 0, stream>>>(sub, idx, Ws, bs, Wp, wa, ws);
  k_main<<<NBLK, 256, 0, stream>>>(prot, sub, idx, out, ws);
  k_finish<<<WBLK, 1024, 0, stream>>>(prot, sub, idx, Wp, bp, sub_out, prot_out,
                                      ws, out);
}

// Round 8
// 149.676 us; speedup vs baseline: 1.4825x; 1.0093x over previous
//
#include <hip/hip_runtime.h>
#include <math.h>

#define N_PROT 50000
#define N_SUB  2000
#define D_PROT 256
#define D_SUB  256
#define D_PROJ 128
#define KW     16
#define N_INT  64
#define NWIN   (N_PROT - KW + 1)

// output layout (floats)
#define OUT_SUB (N_PROT * D_PROT)                 // 12,800,000
#define OUT_IDX (OUT_SUB + N_SUB * D_SUB)         // 13,312,000

// ws layout (floats)
#define WS_PACK  0                                // [0..1] packed argmax u64
#define WS_REACT 2                                // [2..129] reaction
#define WS_CNT   130                              // done-counter (uint)
#define WS_U1    132                              // u1 = Wp @ w1 (256)
#define WS_U2    388                              // u2 = Wp @ ones (256)
#define WS_G     644                              // g[N_PROT] (no constant term)
#define WS_P     (WS_G + N_PROT)                  // P[N_PROT] (no constant term)

#define PB 1563                                   // 1563*32 = 50016 >= 50000 rows
#define SB 64                                     // sub-copy blocks
#define NBLK (PB + SB)
#define WBLK ((NWIN + 1023) / 1024)               // 49 window blocks (1024 thr)

typedef float v4f __attribute__((ext_vector_type(4)));  // NT-store-compatible

// ---- wave64 sum via DPP (VALU pipe only, no DS ops). Result in lane 63. ----
__device__ __forceinline__ float wave_sum64(float x) {
  int v;
  v = __builtin_amdgcn_update_dpp(0, __float_as_int(x), 0x111, 0xf, 0xf, true);
  x += __int_as_float(v);                         // row_shr:1
  v = __builtin_amdgcn_update_dpp(0, __float_as_int(x), 0x112, 0xf, 0xf, true);
  x += __int_as_float(v);                         // row_shr:2
  v = __builtin_amdgcn_update_dpp(0, __float_as_int(x), 0x114, 0xf, 0xf, true);
  x += __int_as_float(v);                         // row_shr:4
  v = __builtin_amdgcn_update_dpp(0, __float_as_int(x), 0x118, 0xf, 0xf, true);
  x += __int_as_float(v);                         // row_shr:8
  v = __builtin_amdgcn_update_dpp(0, __float_as_int(x), 0x142, 0xf, 0xf, true);
  x += __int_as_float(v);                         // row_bcast:15
  v = __builtin_amdgcn_update_dpp(0, __float_as_int(x), 0x143, 0xf, 0xf, true);
  x += __int_as_float(v);                         // row_bcast:31 -> lane63 = full sum
  return x;
}

// =================== K0: reaction + u1/u2 + counters (2 blocks) ==============
__global__ __launch_bounds__(256) void k_prep(
    const float* __restrict__ sub_node, const int* __restrict__ int_index,
    const float* __restrict__ Ws, const float* __restrict__ bs,
    const float* __restrict__ Wp, const float* __restrict__ wa,
    float* __restrict__ ws) {
  const int tid = threadIdx.x;
  if (blockIdx.x == 0) {
    __shared__ int   sidx[N_INT];
    __shared__ float ssum[D_SUB];
    if (tid < N_INT) sidx[tid] = int_index[tid];
    __syncthreads();
    float acc = 0.f;
    #pragma unroll 8
    for (int i = 0; i < N_INT; ++i) acc += sub_node[sidx[i] * D_SUB + tid];
    ssum[tid] = acc;
    __syncthreads();
    if (tid < D_PROJ) {
      float r = 64.0f * bs[tid];
      #pragma unroll 8
      for (int d = 0; d < D_SUB; ++d) r = fmaf(ssum[d], Ws[d * D_PROJ + tid], r);
      ws[WS_REACT + tid] = r;
    }
    if (tid == 0) {
      *((unsigned long long*)ws) = 0ull;          // WS_PACK
      ((unsigned int*)ws)[WS_CNT] = 0u;           // done-counter
    }
  } else {
    // u1[k] = sum_j Wp[k][j] * wa[j];  u2[k] = sum_j Wp[k][j]
    __shared__ float swa[D_PROJ];
    if (tid < D_PROJ) swa[tid] = wa[tid];
    __syncthreads();
    float s1 = 0.f, s2 = 0.f;
    const float4* wrow = (const float4*)&Wp[tid * D_PROJ];
    #pragma unroll 8
    for (int j4 = 0; j4 < D_PROJ / 4; ++j4) {
      float4 w = wrow[j4];
      float4 a = *(const float4*)&swa[j4 * 4];
      s1 = fmaf(w.x, a.x, fmaf(w.y, a.y, fmaf(w.z, a.z, fmaf(w.w, a.w, s1))));
      s2 += w.x + w.y + w.z + w.w;
    }
    ws[WS_U1 + tid] = s1;
    ws[WS_U2 + tid] = s2;
  }
}

// =================== K1: stream prot->out + g/P; sub-copy ====================
// v7b: copy stores are NONTEMPORAL (write-once data; keep 53 MB of streaming
// writes out of the 4 MiB/XCD L2s so prot reads + ws lines stay resident).
// g/P stores stay normal (re-read by k_finish). NT sites use ext_vector v4f.
__global__ __launch_bounds__(256, 4) void k_main(
    const float* __restrict__ prot, const float* __restrict__ sub_node,
    const int* __restrict__ int_index, float* __restrict__ out,
    float* __restrict__ ws) {
  const int tid = threadIdx.x, lane = tid & 63, wave = tid >> 6;
  const int b = blockIdx.x;
  if (b < PB) {
    const v4f c1 = *(const v4f*)&ws[WS_U1 + lane * 4];
    const v4f c2 = *(const v4f*)&ws[WS_U2 + lane * 4];
    const int rbase = b * 32 + wave * 8;
    if (rbase + 8 <= N_PROT) {
      v4f av[8];
      #pragma unroll
      for (int i = 0; i < 8; ++i)
        av[i] = *(const v4f*)&prot[(rbase + i) * D_PROT + lane * 4];
      #pragma unroll
      for (int i = 0; i < 8; ++i)
        __builtin_nontemporal_store(av[i],
            (v4f*)&out[(rbase + i) * D_PROT + lane * 4]);
      #pragma unroll
      for (int i = 0; i < 8; ++i) {
        float g = av[i].x * c1.x + av[i].y * c1.y + av[i].z * c1.z + av[i].w * c1.w;
        float p = av[i].x * c2.x + av[i].y * c2.y + av[i].z * c2.z + av[i].w * c2.w;
        g = wave_sum64(g);
        p = wave_sum64(p);
        if (lane == 63) {
          const int r = rbase + i;
          ws[WS_G + r] = g; ws[WS_P + r] = p;
        }
      }
    } else {
      for (int i = 0; i < 8; ++i) {
        const int r = rbase + i;
        if (r >= N_PROT) break;
        const v4f av = *(const v4f*)&prot[r * D_PROT + lane * 4];
        __builtin_nontemporal_store(av, (v4f*)&out[r * D_PROT + lane * 4]);
        float g = av.x * c1.x + av.y * c1.y + av.z * c1.z + av.w * c1.w;
        float p = av.x * c2.x + av.y * c2.y + av.z * c2.z + av.w * c2.w;
        g = wave_sum64(g);
        p = wave_sum64(p);
        if (lane == 63) { ws[WS_G + r] = g; ws[WS_P + r] = p; }
      }
    }
  } else {
    const int sb = b - PB;                        // 64 blocks, 2048 float4 each
    #pragma unroll
    for (int i = 0; i < 8; ++i) {
      const int gi = sb * 2048 + i * 256 + tid;
      if (gi < (N_SUB * D_SUB) / 4)
        __builtin_nontemporal_store(*(const v4f*)&sub_node[gi * 4],
                                    (v4f*)&out[OUT_SUB + gi * 4]);
    }
    if (sb == 0 && tid < N_INT) out[OUT_IDX + tid] = (float)int_index[tid];
  }
}

// =================== K2: window argmax + last-block parallel patch ===========
__global__ __launch_bounds__(1024) void k_finish(
    const float* __restrict__ prot, const float* __restrict__ sub_node,
    const int* __restrict__ int_index, const float* __restrict__ Wp,
    const float* __restrict__ bp, const float* __restrict__ sub_out,
    const float* __restrict__ prot_out, float* __restrict__ ws,
    float* __restrict__ out) {
  __shared__ float sg[1024 + KW], sp[1024 + KW];
  __shared__ unsigned long long wred[16];
  __shared__ int slast;
  const int tid = threadIdx.x;
  const int w0 = blockIdx.x * 1024;
  for (int i = tid; i < 1024 + KW - 1; i += 1024) {
    int idx = w0 + i;
    bool ok = idx < N_PROT;
    sg[i] = ok ? ws[WS_G + idx] : -1e30f;
    sp[i] = ok ? ws[WS_P + idx] : 0.f;
  }
  __syncthreads();
  {
    int w = w0 + tid;
    unsigned long long best = 0ull;
    if (w < NWIN) {
      float m = sg[tid];
      #pragma unroll
      for (int k = 1; k < KW; ++k) m = fmaxf(m, sg[tid + k]);
      float s = 0.f, t = 0.f;
      #pragma unroll
      for (int k = 0; k < KW; ++k) {
        float e = expf(sg[tid + k] - m);
        s += e;
        t = fmaf(e, sp[tid + k], t);
      }
      t /= s;   // + const dropped: argmax-invariant
      unsigned int bb = __float_as_uint(t);
      unsigned int u = bb ^ ((bb & 0x80000000u) ? 0xFFFFFFFFu : 0x80000000u);
      best = ((unsigned long long)u << 32) |
             (unsigned long long)(0xFFFFFFFFu - (unsigned)w);
    }
    #pragma unroll
    for (int off = 32; off > 0; off >>= 1) {
      unsigned long long o = __shfl_xor(best, off, 64);
      if (o > best) best = o;
    }
    if ((tid & 63) == 0) wred[tid >> 6] = best;
  }
  __syncthreads();
  if (tid == 0) {
    unsigned long long b2 = wred[0];
    for (int i = 1; i < 16; ++i) if (wred[i] > b2) b2 = wred[i];
    atomicMax((unsigned long long*)ws, b2);
    __threadfence();                               // release my atomicMax
    unsigned int ticket = atomicAdd(&((unsigned int*)ws)[WS_CNT], 1u);
    slast = (ticket == WBLK - 1) ? 1 : 0;
  }
  __syncthreads();
  if (!slast) return;

  // -------- last block (1024 thr): all atomicMax's globally visible ----------
  __shared__ float aprot[KW][D_PROT];              // 16 KB
  __shared__ float attn[KW];
  __shared__ float v[D_PROT];                      // attn-weighted window row
  __shared__ float part[8][D_PROJ];                // ts partials
  __shared__ float ts[D_PROJ];
  __shared__ float partP[4][D_PROT], partS[4][D_PROT];
  __shared__ float pdelta[D_PROT], sdelta[D_SUB];
  __shared__ int   sidx[N_INT];
  __shared__ int   swtop;
  if (tid == 0) {
    unsigned long long pk = atomicMax((unsigned long long*)ws, 0ull);
    swtop = (int)(0xFFFFFFFFu - (unsigned)(pk & 0xFFFFFFFFull));
  }
  __syncthreads();
  const int wtop = swtop;
  {  // load the 16 window rows (1024 float4's, one per thread)
    const int row = tid >> 6, c4 = (tid & 63) * 4;
    *(float4*)&aprot[row][c4] = *(const float4*)&prot[(wtop + row) * D_PROT + c4];
  }
  if (tid < N_INT) sidx[tid] = int_index[tid];
  if (tid == 0) {   // softmax over g window (shift-invariant vs ref)
    float m = ws[WS_G + wtop];
    for (int k = 1; k < KW; ++k) m = fmaxf(m, ws[WS_G + wtop + k]);
    float e[KW], s = 0.f;
    for (int k = 0; k < KW; ++k) { e[k] = expf(ws[WS_G + wtop + k] - m); s += e[k]; }
    for (int k = 0; k < KW; ++k) attn[k] = e[k] / s;
  }
  __syncthreads();
  if (tid < D_PROT) {  // v = attn @ A_window  (exploits sum(attn)=1 for bp term)
    float a = 0.f;
    #pragma unroll
    for (int k = 0; k < KW; ++k) a = fmaf(attn[k], aprot[k][tid], a);
    v[tid] = a;
  }
  __syncthreads();
  {  // ts partials: ts[j] = react[j] + bp[j] + sum_d v[d]*Wp[d][j]
    const int j = tid & 127, s = tid >> 7;        // 8 slices x 32 d
    float p = 0.f;
    const float* wp = Wp + (s * 32) * D_PROJ + j;
    #pragma unroll 8
    for (int d = 0; d < 32; ++d) p = fmaf(v[s * 32 + d], wp[d * D_PROJ], p);
    part[s][j] = p;
  }
  __syncthreads();
  if (tid < D_PROJ) {
    float a = ws[WS_REACT + tid] + bp[tid];
    #pragma unroll
    for (int s = 0; s < 8; ++s) a += part[s][tid];
    ts[tid] = a;
  }
  __syncthreads();
  {  // pdelta/sdelta partials: 4 slices x 32 j each, coalesced over d
    const int d = tid & 255, s = tid >> 8;
    float pp = 0.f, ss = 0.f;
    #pragma unroll 8
    for (int j = 0; j < 32; ++j) {
      const float t = ts[s * 32 + j];
      pp = fmaf(t, prot_out[(s * 32 + j) * D_PROT + d], pp);
      ss = fmaf(t, sub_out[(s * 32 + j) * D_SUB + d], ss);
    }
    partP[s][d] = pp; partS[s][d] = ss;
  }
  __syncthreads();
  if (tid < D_PROT) {
    pdelta[tid] = partP[0][tid] + partP[1][tid] + partP[2][tid] + partP[3][tid];
    sdelta[tid] = partS[0][tid] + partS[1][tid] + partS[2][tid] + partS[3][tid];
  }
  __syncthreads();
  {  // write 16 prot rows
    const int row = tid >> 6, c4 = (tid & 63) * 4;
    float4 a = *(float4*)&aprot[row][c4];
    float4 d = *(float4*)&pdelta[c4];
    a.x += d.x; a.y += d.y; a.z += d.z; a.w += d.w;
    *(float4*)&out[(wtop + row) * D_PROT + c4] = a;
  }
  #pragma unroll
  for (int it = 0; it < 4; ++it) {  // write 64 sub rows (dups: same value)
    const int f = tid + it * 1024;                // 4096 float4 over 64 rows
    const int row = f >> 6, c4 = (f & 63) * 4;
    const int rr = sidx[row];
    float4 sv = *(const float4*)&sub_node[rr * D_SUB + c4];
    float4 d = *(float4*)&sdelta[c4];
    sv.x += d.x; sv.y += d.y; sv.z += d.z; sv.w += d.w;
    *(float4*)&out[OUT_SUB + rr * D_SUB + c4] = sv;
  }
}

extern "C" void kernel_launch(void* const* d_in, const int* in_sizes, int n_in,
                              void* d_out, int out_size, void* d_ws, size_t ws_size,
                              hipStream_t stream) {
  const float* prot     = (const float*)d_in[0];
  const float* sub      = (const float*)d_in[1];
  const int*   idx      = (const int*)d_in[2];
  const float* Wp       = (const float*)d_in[3];
  const float* bp       = (const float*)d_in[4];
  const float* Ws       = (const float*)d_in[5];
  const float* bs       = (const float*)d_in[6];
  const float* wa       = (const float*)d_in[7];
  // d_in[8] = ba unused (cancels in softmax); wa[128:] unused (constant in g)
  const float* sub_out  = (const float*)d_in[9];
  const float* prot_out = (const float*)d_in[10];
  float* out = (float*)d_out;
  float* ws  = (float*)d_ws;

  k_prep<<<2, 256, 0, stream>>>(sub, idx, Ws, bs, Wp, wa, ws);
  k_main<<<NBLK, 256, 0, stream>>>(prot, sub, idx, out, ws);
  k_finish<<<WBLK, 1024, 0, stream>>>(prot, sub, idx, Wp, bp, sub_out, prot_out,
                                      ws, out);
}